// Round 10
// baseline (914.108 us; speedup 1.0000x reference)
//
#include <hip/hip_runtime.h>

#define CH 128
#define EPB 2048      // edges per block in bucket passes (8 per thread)
#define RPB 256       // rows per bucket (8-bit local row, 24-bit packed col)
#define MAXBUK 1024   // max buckets supported (totalRows <= 256K)
#define MAXBLK 2048   // max blocks in bucket passes

typedef __attribute__((ext_vector_type(8))) short short8;
typedef __attribute__((ext_vector_type(4))) float floatx4;

__device__ __forceinline__ float bf2f(unsigned short u) {
    union { unsigned int i; float f; } v; v.i = ((unsigned int)u) << 16; return v.f;
}
__device__ __forceinline__ unsigned short f2bf(float f) {
    union { float f; unsigned int i; } v; v.f = f;
    unsigned int r = v.i + 0x7FFF + ((v.i >> 16) & 1);  // RNE
    return (unsigned short)(r >> 16);
}

// ---------------- utility kernels ----------------

// all 20 weight mats (8 Ws, 6 Wh, 6 Wl) f32 (k,n) -> one bf16 arena (n,k)
__global__ __launch_bounds__(256) void k_wt_all(const float* __restrict__ Ws,
                                                const float* __restrict__ Wh,
                                                const float* __restrict__ Wl,
                                                unsigned short* __restrict__ WT) {
    int i = blockIdx.x * 256 + threadIdx.x;
    if (i >= (20 << 14)) return;
    int mat = i >> 14, rem = i & 16383;
    int k = rem >> 7, n = rem & 127;
    float w;
    if (mat < 8)       w = Ws[(mat << 14) + rem];
    else if (mat < 14) w = Wh[((mat - 8) << 14) + rem];
    else               w = Wl[((mat - 14) << 14) + rem];
    WT[(mat << 14) + (n << 7) + k] = f2bf(w);
}

// ---------------- CSR build: two-level bucketing, ZERO global atomics ------
// UNIFIED row space: one row per (rank, simplex) = totalN rows. All three
// edge classes (adj, h2l, l2h) merge into ONE CSR row. The col field is
// pre-offset to address a SIX-slot y arena (S/H/L x even/odd target-rank
// parity, exact slot sizes) so the whole layer runs as two GEMM dispatches
// + two gather dispatches. Bucket entry: int2{ (lrow<<24)|(col+coff), val },
// lrow = 8-bit bucket-local row, col+coff < 720K < 2^24.

struct Segs {
    const int*   row[10];
    const int*   col[10];
    const float* val[10];
    int base[10];    // row-space base in unified row arena
    int coff[10];    // col offset into y arena (slot base, row units)
    int nnz[10];
    int start[10];   // first block of this segment
};

__device__ __forceinline__ int seg_of(const Segs& sg, int blk) {
    int s = 0;
    for (int k = 1; k < 10; ++k) if (blk >= sg.start[k]) s = k;
    return s;
}

__global__ __launch_bounds__(256) void k_bkt_count(Segs sg, int nbuk, int* __restrict__ M) {
    __shared__ int lcnt[MAXBUK];
    int s = seg_of(sg, blockIdx.x);
    int t = threadIdx.x;
    int b0 = (blockIdx.x - sg.start[s]) * EPB;
    int nnz = sg.nnz[s];
    const int* __restrict__ rowp = sg.row[s];
    int sbase = sg.base[s];
    for (int j = t; j < nbuk; j += 256) lcnt[j] = 0;
    __syncthreads();
#pragma unroll
    for (int k = 0; k < 8; ++k) {
        int i = b0 + k * 256 + t;
        if (i < nnz) atomicAdd(&lcnt[(sbase + rowp[i]) >> 8], 1);
    }
    __syncthreads();
    int* Mr = M + (size_t)blockIdx.x * nbuk;
    for (int j = t; j < nbuk; j += 256) Mr[j] = lcnt[j];
}

// block b: exclusive-scan column b of M in place; colsum[b] = total
__global__ __launch_bounds__(256) void k_colscan(int* __restrict__ M, int nblk, int nbuk,
                                                 int* __restrict__ colsum) {
    __shared__ int a[2][MAXBLK];
    int b = blockIdx.x, t = threadIdx.x;
    for (int j = t; j < MAXBLK; j += 256) a[0][j] = (j < nblk) ? M[(size_t)j * nbuk + b] : 0;
    __syncthreads();
    int src = 0;
    for (int off = 1; off < MAXBLK; off <<= 1) {
        for (int j = t; j < MAXBLK; j += 256) {
            int v = a[src][j];
            if (j >= off) v += a[src][j - off];
            a[src ^ 1][j] = v;
        }
        __syncthreads();
        src ^= 1;
    }
    for (int j = t; j < nblk; j += 256)
        M[(size_t)j * nbuk + b] = (j == 0) ? 0 : a[src][j - 1];
    if (t == 0) colsum[b] = a[src][nblk - 1];
}

__global__ __launch_bounds__(256) void k_bkt_scan(const int* __restrict__ colsum, int nbuk,
                                                  int* __restrict__ bucketBase,
                                                  int* __restrict__ rowptr_last) {
    __shared__ int a[2][MAXBUK];
    int t = threadIdx.x;
    for (int j = t; j < MAXBUK; j += 256) a[0][j] = (j < nbuk) ? colsum[j] : 0;
    __syncthreads();
    int src = 0;
    for (int off = 1; off < MAXBUK; off <<= 1) {
        for (int j = t; j < MAXBUK; j += 256) {
            int v = a[src][j];
            if (j >= off) v += a[src][j - off];
            a[src ^ 1][j] = v;
        }
        __syncthreads();
        src ^= 1;
    }
    for (int j = t; j < nbuk; j += 256) bucketBase[j] = (j == 0) ? 0 : a[src][j - 1];
    if (t == 0) { bucketBase[nbuk] = a[src][nbuk - 1]; *rowptr_last = a[src][nbuk - 1]; }
}

__global__ __launch_bounds__(256) void k_bkt_scatter(Segs sg, int nbuk,
                                                     const int* __restrict__ M,  // per-(block,bucket) prefix
                                                     const int* __restrict__ bucketBase,
                                                     int2* __restrict__ bcv) {
    __shared__ int lcnt[MAXBUK];
    __shared__ int lbase[MAXBUK];
    int s = seg_of(sg, blockIdx.x);
    int t = threadIdx.x;
    int b0 = (blockIdx.x - sg.start[s]) * EPB;
    int nnz = sg.nnz[s];
    const int* __restrict__ rowp = sg.row[s];
    const int* __restrict__ colp = sg.col[s];
    const float* __restrict__ valp = sg.val[s];
    int sbase = sg.base[s];
    int scoff = sg.coff[s];
    for (int j = t; j < nbuk; j += 256) lcnt[j] = 0;
    __syncthreads();
    int rank[8], grow[8];
#pragma unroll
    for (int k = 0; k < 8; ++k) {
        int i = b0 + k * 256 + t;
        if (i < nnz) {
            grow[k] = sbase + rowp[i];
            rank[k] = atomicAdd(&lcnt[grow[k] >> 8], 1);
        }
    }
    __syncthreads();
    const int* Mr = M + (size_t)blockIdx.x * nbuk;
    for (int j = t; j < nbuk; j += 256) lbase[j] = bucketBase[j] + Mr[j];
    __syncthreads();
#pragma unroll
    for (int k = 0; k < 8; ++k) {
        int i = b0 + k * 256 + t;
        if (i < nnz) {
            int pos = lbase[grow[k] >> 8] + rank[k];
            int packed = ((grow[k] & (RPB - 1)) << 24) | (colp[i] + scoff);
            bcv[pos] = make_int2(packed, __float_as_int(valp[i]));
        }
    }
}

__global__ __launch_bounds__(256) void k_bkt_csr(const int2* __restrict__ bcv,
                                                 const int* __restrict__ bucketBase,
                                                 int* __restrict__ rowptr, int totalRows,
                                                 int2* __restrict__ edg) {
    __shared__ int ptr[RPB];
    __shared__ int swt[4];
    int b = blockIdx.x, t = threadIdx.x;
    int bb = bucketBase[b], be = bucketBase[b + 1];
    int bsz = be - bb;
    int rowLo = b << 8;
    ptr[t] = 0;
    __syncthreads();
    for (int i = t; i < bsz; i += 256)
        atomicAdd(&ptr[((unsigned)bcv[bb + i].x) >> 24], 1);
    __syncthreads();
    // exclusive scan of ptr[0..255]; one slot per thread
    int c = ptr[t];
    int lane = t & 63, w = t >> 6;
    int incl = c;
    for (int off = 1; off < 64; off <<= 1) {
        int u = __shfl_up(incl, off, 64);
        if (lane >= off) incl += u;
    }
    if (lane == 63) swt[w] = incl;
    __syncthreads();
    int waveoff = 0;
    for (int k = 0; k < w; ++k) waveoff += swt[k];
    int run = waveoff + incl - c;   // exclusive prefix within bucket
    ptr[t] = run;
    if (rowLo + t < totalRows) rowptr[rowLo + t] = bb + run;
    __syncthreads();
    for (int i = t; i < bsz; i += 256) {
        int2 e = bcv[bb + i];
        int lrow = ((unsigned)e.x) >> 24;
        int pos = atomicAdd(&ptr[lrow], 1);
        edg[bb + pos] = make_int2(e.x & 0x00FFFFFF, e.y);
    }
}

// ---------------- GEMM: Y(MxC) = A(MxC) @ B(CxC), multi-job ----------------
// sA-only LDS (32 KB -> 5 blocks/CU). B (one 32 KB weight matrix per job,
// identical addresses across all blocks of the job) is read directly from
// global inside the MFMA loop: stays L2-resident, 32 independent 16 B/lane
// loads pipeline under MFMA, and the freed LDS buys 2.5x the resident waves.

__device__ __forceinline__ int lds_idx(int r, int koff) {
    return (r << 7) + ((((koff >> 3) ^ (r & 15))) << 3);
}

__device__ __forceinline__ void gemm_core(const unsigned short* sA,
                                          const unsigned short* __restrict__ Bt,
                                          unsigned short* __restrict__ Y, int M, int row0, int t) {
    const int wave = t >> 6;
    const int lane = t & 63;
    const int quad = lane >> 4;
    const int l16  = lane & 15;
    const int rbase = wave * 32;

    floatx4 acc[2][8];
    for (int i = 0; i < 2; ++i)
        for (int j = 0; j < 8; ++j) acc[i][j] = (floatx4){0.f, 0.f, 0.f, 0.f};

    for (int kk = 0; kk < 4; ++kk) {
        int ko = kk * 32 + quad * 8;
        short8 a0 = *(const short8*)(&sA[lds_idx(rbase + l16, ko)]);
        short8 a1 = *(const short8*)(&sA[lds_idx(rbase + 16 + l16, ko)]);
        const unsigned short* bp = Bt + (l16 << 7) + ko;
        for (int j = 0; j < 8; ++j) {
            short8 b = *(const short8*)(bp + (j << 11));   // row j*16+l16 of Bt
            acc[0][j] = __builtin_amdgcn_mfma_f32_16x16x32_bf16(a0, b, acc[0][j], 0, 0, 0);
            acc[1][j] = __builtin_amdgcn_mfma_f32_16x16x32_bf16(a1, b, acc[1][j], 0, 0, 0);
        }
    }

    for (int i = 0; i < 2; ++i) {
        int rg0 = row0 + rbase + i * 16 + quad * 4;
        for (int reg = 0; reg < 4; ++reg) {
            int rg = rg0 + reg;
            if (rg >= M) continue;
            unsigned short* yr = Y + (size_t)rg * CH;
            for (int j = 0; j < 8; ++j)
                yr[j * 16 + l16] = f2bf(acc[i][j][reg]);
        }
    }
}

struct GJobs {
    const void* A[6];
    const unsigned short* Bt[6];
    unsigned short* Y[6];
    int M[6];
    int bstart[7];   // bstart[njobs] = total blocks
    int njobs;
};

__global__ __launch_bounds__(256) void k_gemm_multi(GJobs g) {
    __shared__ __align__(16) unsigned short sA[128 * 128];
    const int t = threadIdx.x;
    int b = blockIdx.x;
    int j = 0;
    while (j + 1 < g.njobs && b >= g.bstart[j + 1]) ++j;
    const unsigned short* A = (const unsigned short*)g.A[j];
    const unsigned short* Bt = g.Bt[j];
    unsigned short* Y = g.Y[j];
    int M = g.M[j];
    const int row0 = (b - g.bstart[j]) * 128;

    for (int it = 0; it < 8; ++it) {
        int chunk = it * 256 + t;
        int r = chunk >> 4;
        int cidx = chunk & 15;
        int coff = cidx << 3;
        int sidx = (r << 7) + (((cidx ^ (r & 15))) << 3);
        int gr = row0 + r;
        float4 av = make_float4(0.f, 0.f, 0.f, 0.f);
        if (gr < M) av = *(const float4*)(A + (size_t)gr * CH + coff);
        *(float4*)(&sA[sidx]) = av;
    }
    __syncthreads();
    gemm_core(sA, Bt, Y, M, row0, t);
}

// A in f32 (layer-1 inputs); converts to bf16 during staging
__global__ __launch_bounds__(256) void k_gemm_multi_f32(GJobs g) {
    __shared__ __align__(16) unsigned short sA[128 * 128];
    const int t = threadIdx.x;
    int b = blockIdx.x;
    int j = 0;
    while (j + 1 < g.njobs && b >= g.bstart[j + 1]) ++j;
    const float* A = (const float*)g.A[j];
    const unsigned short* Bt = g.Bt[j];
    unsigned short* Y = g.Y[j];
    int M = g.M[j];
    const int row0 = (b - g.bstart[j]) * 128;

    for (int it = 0; it < 8; ++it) {
        int chunk = it * 256 + t;
        int r = chunk >> 4;
        int cidx = chunk & 15;
        int coff = cidx << 3;
        int sidx = (r << 7) + (((cidx ^ (r & 15))) << 3);
        int gr = row0 + r;
        unsigned short us[8];
        if (gr < M) {
            const float* ar = A + (size_t)gr * CH + coff;
            float4 f0 = *(const float4*)ar;
            float4 f1 = *(const float4*)(ar + 4);
            us[0] = f2bf(f0.x); us[1] = f2bf(f0.y); us[2] = f2bf(f0.z); us[3] = f2bf(f0.w);
            us[4] = f2bf(f1.x); us[5] = f2bf(f1.y); us[6] = f2bf(f1.z); us[7] = f2bf(f1.w);
        } else {
            for (int k = 0; k < 8; ++k) us[k] = 0;
        }
        *(float4*)(&sA[sidx]) = *(const float4*)us;
    }
    __syncthreads();
    gemm_core(sA, Bt, Y, M, row0, t);
}

// ---------------- fused gather + sigmoid (unified edge list) --------------
// one wave per unified row (~12 edges, one contiguous range, one y arena).
// 8-wide double-buffered pipeline: batch k+1's 8 gathers are issued before
// batch k's FMAs, so 8-16 loads are in flight per wave.

__device__ __forceinline__ void g_load(const int2* __restrict__ eg, int j, int n,
                                       const unsigned short* __restrict__ y, int coff,
                                       int2* e, unsigned int* u) {
#pragma unroll
    for (int k = 0; k < 8; ++k) {
        if (k < n) {
            e[k] = eg[j + k];
            u[k] = *(const unsigned int*)(y + (((size_t)(unsigned)e[k].x) << 7) + coff);
        }
    }
}

__device__ __forceinline__ void g_acc(const int2* e, const unsigned int* u, int n,
                                      float& a0, float& a1) {
#pragma unroll
    for (int k = 0; k < 8; ++k) {
        if (k < n) {
            float v = __int_as_float(e[k].y);
            a0 += v * __int_as_float(u[k] << 16);
            a1 += v * __int_as_float(u[k] & 0xffff0000u);
        }
    }
}

__global__ __launch_bounds__(256) void k_gather(
    const int* __restrict__ rp, const unsigned short* __restrict__ y,
    const int2* __restrict__ eArena,
    unsigned short* __restrict__ xout, int M)
{
    int wrow = blockIdx.x * 4 + (threadIdx.x >> 6);
    if (wrow >= M) return;
    wrow = __builtin_amdgcn_readfirstlane(wrow);
    int lane = threadIdx.x & 63;
    int coff = lane * 2;
    float a0 = 0.f, a1 = 0.f;

    int jb = __builtin_amdgcn_readfirstlane(rp[wrow]);
    int je = __builtin_amdgcn_readfirstlane(rp[wrow + 1]);
    int j = jb;
    int2 ea[8]; unsigned int ua[8];
    int2 eb[8]; unsigned int ub[8];
    int n0 = je - j; if (n0 > 8) n0 = 8;
    if (n0 > 0) g_load(eArena, j, n0, y, coff, ea, ua);
    j += n0;
    while (j < je) {
        int n1 = je - j; if (n1 > 8) n1 = 8;
        g_load(eArena, j, n1, y, coff, eb, ub);
        j += n1;
        g_acc(ea, ua, n0, a0, a1);
#pragma unroll
        for (int k = 0; k < 8; ++k) {
            if (k < n1) { ea[k] = eb[k]; ua[k] = ub[k]; }
        }
        n0 = n1;
    }
    if (n0 > 0) g_acc(ea, ua, n0, a0, a1);

    float s0 = 1.0f / (1.0f + __expf(-a0));
    float s1 = 1.0f / (1.0f + __expf(-a1));
    ushort2 o;
    o.x = f2bf(s0);
    o.y = f2bf(s1);
    *(ushort2*)(xout + (size_t)wrow * CH + coff) = o;
}

// ---------------- output head ----------------

__global__ __launch_bounds__(128) void k_out(const unsigned short* __restrict__ x0,
                                             const float* __restrict__ Wout,
                                             const float* __restrict__ bout,
                                             float* __restrict__ out, int M) {
    __shared__ float sl[8][16];
    int rlocal = threadIdx.x >> 4;
    int o = threadIdx.x & 15;
    int rowi = blockIdx.x * 8 + rlocal;
    float acc = 0.f;
    if (rowi < M && o < 10) {
        const unsigned short* xr = x0 + (size_t)rowi * CH;
        for (int k = 0; k < CH; ++k)
            acc += bf2f(xr[k]) * Wout[k * 10 + o];
        acc += bout[o];
    }
    sl[rlocal][o] = acc;
    __syncthreads();
    if (rowi < M && o < 10) {
        float mx = -1e30f;
        for (int j = 0; j < 10; ++j) mx = fmaxf(mx, sl[rlocal][j]);
        float s = 0.f;
        for (int j = 0; j < 10; ++j) s += __expf(sl[rlocal][j] - mx);
        out[rowi * 10 + o] = __expf(sl[rlocal][o] - mx) / s;
    }
}

// ---------------- launch ----------------

extern "C" void kernel_launch(void* const* d_in, const int* in_sizes, int n_in,
                              void* d_out, int out_size, void* d_ws, size_t ws_size,
                              hipStream_t stream) {
    const float* xin[4];
    for (int r = 0; r < 4; ++r) xin[r] = (const float*)d_in[r];
    const int* arow[4]; const int* acol[4]; const float* aval[4];
    for (int r = 0; r < 4; ++r) {
        arow[r] = (const int*)d_in[4 + 3 * r];
        acol[r] = (const int*)d_in[5 + 3 * r];
        aval[r] = (const float*)d_in[6 + 3 * r];
    }
    const int* irow[3]; const int* icol[3]; const float* ival[3];
    for (int r = 0; r < 3; ++r) {
        irow[r] = (const int*)d_in[16 + 3 * r];
        icol[r] = (const int*)d_in[17 + 3 * r];
        ival[r] = (const float*)d_in[18 + 3 * r];
    }
    const float* W_same = (const float*)d_in[25];
    const float* W_h2l  = (const float*)d_in[26];
    const float* W_l2h  = (const float*)d_in[27];
    const float* W_out  = (const float*)d_in[28];
    const float* b_out  = (const float*)d_in[29];

    int Nr[4], adjnnz[4], incnnz[3];
    for (int r = 0; r < 4; ++r) { Nr[r] = in_sizes[r] / CH; adjnnz[r] = in_sizes[4 + 3 * r]; }
    for (int r = 0; r < 3; ++r) incnnz[r] = in_sizes[16 + 3 * r];
    size_t totalN = (size_t)Nr[0] + Nr[1] + Nr[2] + Nr[3];
    size_t totAdj = 0; for (int r = 0; r < 4; ++r) totAdj += adjnnz[r];
    size_t totInc = 0; for (int r = 0; r < 3; ++r) totInc += incnnz[r];
    size_t totEdges = totAdj + 2 * totInc;

    // unified row space: one row per (rank, simplex)
    int baseRank[4];
    int acc_rows = 0;
    for (int r = 0; r < 4; ++r) { baseRank[r] = acc_rows; acc_rows += Nr[r]; }
    int totalRowsU = acc_rows;               // == totalN
    int nbuk = (totalRowsU + RPB - 1) >> 8;

    // ---- y arena: 6 exact-size slots (S/H/L x even/odd target parity) ----
    auto imax = [](int a, int b) { return a > b ? a : b; };
    int szSe = imax(Nr[0], Nr[2]), szSo = imax(Nr[1], Nr[3]);
    int szHe = imax(Nr[1], Nr[3]), szHo = Nr[2];
    int szLe = Nr[1],              szLo = imax(Nr[0], Nr[2]);
    int bSe = 0;
    int bSo = bSe + szSe;
    int bHe = bSo + szSo;
    int bHo = bHe + szHe;
    int bLe = bHo + szHo;
    int bLo = bLe + szLe;
    int yRows = bLo + szLo;      // ~600K rows < 2^24

    // ---- workspace ----
    char* ws = (char*)d_ws;
    size_t off = 0;
    auto take = [&](size_t bytes) { char* p = ws + off; off += (bytes + 255) & ~(size_t)255; return p; };
    unsigned short* xbuf   = (unsigned short*)take(totalN * CH * 2);
    unsigned short* yArena = (unsigned short*)take((size_t)yRows * CH * 2);
    unsigned short* WT     = (unsigned short*)take((size_t)20 * 16384 * 2);
    int*  rowptrG = (int*)take(((size_t)totalRowsU + 1) * 4);
    int2* eArena  = (int2*)take(totEdges * 8);
    (void)ws_size;

    unsigned short* WsT = WT;                       // mats 0..7
    unsigned short* WhT = WT + ((size_t)8 << 14);   // mats 8..13
    unsigned short* WlT = WT + ((size_t)14 << 14);  // mats 14..19

    unsigned short* x[4];
    {
        size_t o = 0;
        for (int r = 0; r < 4; ++r) { x[r] = xbuf + o; o += (size_t)Nr[r] * CH; }
    }

    // ---- CSR build ----
    Segs sg;
    int nblk = 0;
    {
        for (int r = 0; r < 4; ++r) {  // adj: rows of rank r, reads S_r slot
            sg.row[r] = arow[r]; sg.col[r] = acol[r]; sg.val[r] = aval[r];
            sg.base[r] = baseRank[r];
            sg.coff[r] = (r & 1) ? bSo : bSe;
            sg.nnz[r] = adjnnz[r]; sg.start[r] = nblk;
            nblk += (adjnnz[r] + EPB - 1) / EPB;
        }
        for (int s = 0; s < 3; ++s) {  // h2l: rows of rank s, cols -> H_s slot
            sg.row[4 + s] = irow[s]; sg.col[4 + s] = icol[s]; sg.val[4 + s] = ival[s];
            sg.base[4 + s] = baseRank[s];
            sg.coff[4 + s] = (s & 1) ? bHo : bHe;
            sg.nnz[4 + s] = incnnz[s]; sg.start[4 + s] = nblk;
            nblk += (incnnz[s] + EPB - 1) / EPB;
        }
        for (int s = 0; s < 3; ++s) {  // l2h: rows of rank s+1, cols -> L_{s+1} slot
            sg.row[7 + s] = icol[s]; sg.col[7 + s] = irow[s]; sg.val[7 + s] = ival[s];
            sg.base[7 + s] = baseRank[s + 1];
            sg.coff[7 + s] = ((s + 1) & 1) ? bLo : bLe;
            sg.nnz[7 + s] = incnnz[s]; sg.start[7 + s] = nblk;
            nblk += (incnnz[s] + EPB - 1) / EPB;
        }

        // CSR-build scratch aliases buffers dead until the layer phase:
        //   bcv  (totEdges*8 = 25.6 MB) <- yArena
        //   M (nblk*nbuk*4 ~ 7 MB) + colsum + bucketBase <- xbuf
        int2* bcv = (int2*)yArena;
        int*  M   = (int*)xbuf;
        int*  colsum     = M + (size_t)nblk * nbuk;
        int*  bucketBase = colsum + nbuk;

        k_bkt_count  <<<nblk, 256, 0, stream>>>(sg, nbuk, M);
        k_colscan    <<<nbuk, 256, 0, stream>>>(M, nblk, nbuk, colsum);
        k_bkt_scan   <<<1,    256, 0, stream>>>(colsum, nbuk, bucketBase, rowptrG + totalRowsU);
        k_bkt_scatter<<<nblk, 256, 0, stream>>>(sg, nbuk, M, bucketBase, bcv);
        k_bkt_csr    <<<nbuk, 256, 0, stream>>>(bcv, bucketBase, rowptrG, totalRowsU, eArena);
    }

    // ---- weights ----
    k_wt_all<<<(20 * 16384 + 255) / 256, 256, 0, stream>>>(W_same, W_h2l, W_l2h, WT);

    // ---- layers: per layer only 4 dispatches ----
    // G01 = {S0,H0,L1, S1,H1,L2} -> g01 (ranks 0,1) -> G23 = {S2,H2,L3, S3} -> g23.
    // Even-parity slots written by G23 (S2,H2) reuse S0/H0's slots, consumed-
    // before-overwrite since g01 precedes G23; L slots: L1->Lo, L2->Le, L3->Lo.
    unsigned short* ySlotS[2] = { yArena + (size_t)bSe * CH, yArena + (size_t)bSo * CH };
    unsigned short* ySlotH[2] = { yArena + (size_t)bHe * CH, yArena + (size_t)bHo * CH };
    unsigned short* ySlotL[2] = { yArena + (size_t)bLe * CH, yArena + (size_t)bLo * CH };

    for (int l = 0; l < 2; ++l) {
        auto Ain = [&](int r) -> const void* {
            return (l == 0) ? (const void*)xin[r] : (const void*)x[r];
        };
        // ---- G01 ----
        {
            GJobs g; int nj = 0;
            auto add = [&](const void* A, const unsigned short* Bt, unsigned short* Y, int M) {
                g.A[nj] = A; g.Bt[nj] = Bt; g.Y[nj] = Y; g.M[nj] = M; ++nj;
            };
            add(Ain(0), WsT + (((size_t)(l * 4 + 0)) << 14), ySlotS[0], Nr[0]);  // S0
            add(Ain(1), WhT + (((size_t)(l * 3 + 0)) << 14), ySlotH[0], Nr[1]);  // H0
            add(Ain(0), WlT + (((size_t)(l * 3 + 0)) << 14), ySlotL[1], Nr[0]);  // L1
            add(Ain(1), WsT + (((size_t)(l * 4 + 1)) << 14), ySlotS[1], Nr[1]);  // S1
            add(Ain(2), WhT + (((size_t)(l * 3 + 1)) << 14), ySlotH[1], Nr[2]);  // H1
            add(Ain(1), WlT + (((size_t)(l * 3 + 1)) << 14), ySlotL[0], Nr[1]);  // L2
            g.njobs = nj;
            int bacc = 0;
            for (int k = 0; k < nj; ++k) { g.bstart[k] = bacc; bacc += (g.M[k] + 127) / 128; }
            g.bstart[nj] = bacc;
            if (l == 0) k_gemm_multi_f32<<<bacc, 256, 0, stream>>>(g);
            else        k_gemm_multi    <<<bacc, 256, 0, stream>>>(g);
        }
        {   // g01: ranks 0,1 -> x0|x1 (contiguous in xbuf)
            int Mg = Nr[0] + Nr[1];
            k_gather<<<(Mg + 3) / 4, 256, 0, stream>>>(rowptrG, yArena, eArena, xbuf, Mg);
        }
        // ---- G23 ----
        {
            GJobs g; int nj = 0;
            auto add = [&](const void* A, const unsigned short* Bt, unsigned short* Y, int M) {
                g.A[nj] = A; g.Bt[nj] = Bt; g.Y[nj] = Y; g.M[nj] = M; ++nj;
            };
            add(Ain(2), WsT + (((size_t)(l * 4 + 2)) << 14), ySlotS[0], Nr[2]);  // S2
            add(Ain(3), WhT + (((size_t)(l * 3 + 2)) << 14), ySlotH[0], Nr[3]);  // H2
            add(Ain(2), WlT + (((size_t)(l * 3 + 2)) << 14), ySlotL[1], Nr[2]);  // L3
            add(Ain(3), WsT + (((size_t)(l * 4 + 3)) << 14), ySlotS[1], Nr[3]);  // S3
            g.njobs = nj;
            int bacc = 0;
            for (int k = 0; k < nj; ++k) { g.bstart[k] = bacc; bacc += (g.M[k] + 127) / 128; }
            g.bstart[nj] = bacc;
            if (l == 0) k_gemm_multi_f32<<<bacc, 256, 0, stream>>>(g);
            else        k_gemm_multi    <<<bacc, 256, 0, stream>>>(g);
        }
        {   // g23: ranks 2,3 -> x2|x3 (contiguous in xbuf)
            int Mg = Nr[2] + Nr[3];
            k_gather<<<(Mg + 3) / 4, 256, 0, stream>>>(rowptrG + baseRank[2], yArena, eArena, x[2], Mg);
        }
    }

    k_out<<<(Nr[0] + 7) / 8, 128, 0, stream>>>(x[0], W_out, b_out, (float*)d_out, Nr[0]);
}

// Round 11
// 784.754 us; speedup vs baseline: 1.1648x; 1.1648x over previous
//
#include <hip/hip_runtime.h>

#define CH 128
#define EPB 2048      // edges per block in bucket passes (8 per thread)
#define RPB 256       // rows per bucket (8-bit local row, 24-bit packed col)
#define MAXBUK 1024   // max buckets supported (totalRows <= 256K)
#define MAXBLK 2048   // max blocks in bucket passes

typedef __attribute__((ext_vector_type(8))) short short8;
typedef __attribute__((ext_vector_type(4))) float floatx4;

__device__ __forceinline__ float bf2f(unsigned short u) {
    union { unsigned int i; float f; } v; v.i = ((unsigned int)u) << 16; return v.f;
}
__device__ __forceinline__ unsigned short f2bf(float f) {
    union { float f; unsigned int i; } v; v.f = f;
    unsigned int r = v.i + 0x7FFF + ((v.i >> 16) & 1);  // RNE
    return (unsigned short)(r >> 16);
}

// ---------------- utility kernels ----------------

// all 20 weight mats (8 Ws, 6 Wh, 6 Wl) f32 (k,n) -> one bf16 arena (n,k)
__global__ __launch_bounds__(256) void k_wt_all(const float* __restrict__ Ws,
                                                const float* __restrict__ Wh,
                                                const float* __restrict__ Wl,
                                                unsigned short* __restrict__ WT) {
    int i = blockIdx.x * 256 + threadIdx.x;
    if (i >= (20 << 14)) return;
    int mat = i >> 14, rem = i & 16383;
    int k = rem >> 7, n = rem & 127;
    float w;
    if (mat < 8)       w = Ws[(mat << 14) + rem];
    else if (mat < 14) w = Wh[((mat - 8) << 14) + rem];
    else               w = Wl[((mat - 14) << 14) + rem];
    WT[(mat << 14) + (n << 7) + k] = f2bf(w);
}

// ---------------- CSR build: two-level bucketing, ZERO global atomics ------
// UNIFIED row space: one row per (rank, simplex) = totalN rows. All three
// edge classes (adj, h2l, l2h) merge into ONE CSR row. The col field is
// pre-offset to address a SIX-slot y arena (S/H/L x even/odd target-rank
// parity, exact slot sizes) so the whole layer runs as two GEMM dispatches
// + two gather dispatches. Bucket entry: int2{ (lrow<<24)|(col+coff), val },
// lrow = 8-bit bucket-local row, col+coff < 720K < 2^24.

struct Segs {
    const int*   row[10];
    const int*   col[10];
    const float* val[10];
    int base[10];    // row-space base in unified row arena
    int coff[10];    // col offset into y arena (slot base, row units)
    int nnz[10];
    int start[10];   // first block of this segment
};

__device__ __forceinline__ int seg_of(const Segs& sg, int blk) {
    int s = 0;
    for (int k = 1; k < 10; ++k) if (blk >= sg.start[k]) s = k;
    return s;
}

__global__ __launch_bounds__(256) void k_bkt_count(Segs sg, int nbuk, int* __restrict__ M) {
    __shared__ int lcnt[MAXBUK];
    int s = seg_of(sg, blockIdx.x);
    int t = threadIdx.x;
    int b0 = (blockIdx.x - sg.start[s]) * EPB;
    int nnz = sg.nnz[s];
    const int* __restrict__ rowp = sg.row[s];
    int sbase = sg.base[s];
    for (int j = t; j < nbuk; j += 256) lcnt[j] = 0;
    __syncthreads();
#pragma unroll
    for (int k = 0; k < 8; ++k) {
        int i = b0 + k * 256 + t;
        if (i < nnz) atomicAdd(&lcnt[(sbase + rowp[i]) >> 8], 1);
    }
    __syncthreads();
    int* Mr = M + (size_t)blockIdx.x * nbuk;
    for (int j = t; j < nbuk; j += 256) Mr[j] = lcnt[j];
}

// block b: exclusive-scan column b of M in place; colsum[b] = total
__global__ __launch_bounds__(256) void k_colscan(int* __restrict__ M, int nblk, int nbuk,
                                                 int* __restrict__ colsum) {
    __shared__ int a[2][MAXBLK];
    int b = blockIdx.x, t = threadIdx.x;
    for (int j = t; j < MAXBLK; j += 256) a[0][j] = (j < nblk) ? M[(size_t)j * nbuk + b] : 0;
    __syncthreads();
    int src = 0;
    for (int off = 1; off < MAXBLK; off <<= 1) {
        for (int j = t; j < MAXBLK; j += 256) {
            int v = a[src][j];
            if (j >= off) v += a[src][j - off];
            a[src ^ 1][j] = v;
        }
        __syncthreads();
        src ^= 1;
    }
    for (int j = t; j < nblk; j += 256)
        M[(size_t)j * nbuk + b] = (j == 0) ? 0 : a[src][j - 1];
    if (t == 0) colsum[b] = a[src][nblk - 1];
}

__global__ __launch_bounds__(256) void k_bkt_scan(const int* __restrict__ colsum, int nbuk,
                                                  int* __restrict__ bucketBase,
                                                  int* __restrict__ rowptr_last) {
    __shared__ int a[2][MAXBUK];
    int t = threadIdx.x;
    for (int j = t; j < MAXBUK; j += 256) a[0][j] = (j < nbuk) ? colsum[j] : 0;
    __syncthreads();
    int src = 0;
    for (int off = 1; off < MAXBUK; off <<= 1) {
        for (int j = t; j < MAXBUK; j += 256) {
            int v = a[src][j];
            if (j >= off) v += a[src][j - off];
            a[src ^ 1][j] = v;
        }
        __syncthreads();
        src ^= 1;
    }
    for (int j = t; j < nbuk; j += 256) bucketBase[j] = (j == 0) ? 0 : a[src][j - 1];
    if (t == 0) { bucketBase[nbuk] = a[src][nbuk - 1]; *rowptr_last = a[src][nbuk - 1]; }
}

__global__ __launch_bounds__(256) void k_bkt_scatter(Segs sg, int nbuk,
                                                     const int* __restrict__ M,  // per-(block,bucket) prefix
                                                     const int* __restrict__ bucketBase,
                                                     int2* __restrict__ bcv) {
    __shared__ int lcnt[MAXBUK];
    __shared__ int lbase[MAXBUK];
    int s = seg_of(sg, blockIdx.x);
    int t = threadIdx.x;
    int b0 = (blockIdx.x - sg.start[s]) * EPB;
    int nnz = sg.nnz[s];
    const int* __restrict__ rowp = sg.row[s];
    const int* __restrict__ colp = sg.col[s];
    const float* __restrict__ valp = sg.val[s];
    int sbase = sg.base[s];
    int scoff = sg.coff[s];
    for (int j = t; j < nbuk; j += 256) lcnt[j] = 0;
    __syncthreads();
    int rank[8], grow[8];
#pragma unroll
    for (int k = 0; k < 8; ++k) {
        int i = b0 + k * 256 + t;
        if (i < nnz) {
            grow[k] = sbase + rowp[i];
            rank[k] = atomicAdd(&lcnt[grow[k] >> 8], 1);
        }
    }
    __syncthreads();
    const int* Mr = M + (size_t)blockIdx.x * nbuk;
    for (int j = t; j < nbuk; j += 256) lbase[j] = bucketBase[j] + Mr[j];
    __syncthreads();
#pragma unroll
    for (int k = 0; k < 8; ++k) {
        int i = b0 + k * 256 + t;
        if (i < nnz) {
            int pos = lbase[grow[k] >> 8] + rank[k];
            int packed = ((grow[k] & (RPB - 1)) << 24) | (colp[i] + scoff);
            bcv[pos] = make_int2(packed, __float_as_int(valp[i]));
        }
    }
}

__global__ __launch_bounds__(256) void k_bkt_csr(const int2* __restrict__ bcv,
                                                 const int* __restrict__ bucketBase,
                                                 int* __restrict__ rowptr, int totalRows,
                                                 int2* __restrict__ edg) {
    __shared__ int ptr[RPB];
    __shared__ int swt[4];
    int b = blockIdx.x, t = threadIdx.x;
    int bb = bucketBase[b], be = bucketBase[b + 1];
    int bsz = be - bb;
    int rowLo = b << 8;
    ptr[t] = 0;
    __syncthreads();
    for (int i = t; i < bsz; i += 256)
        atomicAdd(&ptr[((unsigned)bcv[bb + i].x) >> 24], 1);
    __syncthreads();
    // exclusive scan of ptr[0..255]; one slot per thread
    int c = ptr[t];
    int lane = t & 63, w = t >> 6;
    int incl = c;
    for (int off = 1; off < 64; off <<= 1) {
        int u = __shfl_up(incl, off, 64);
        if (lane >= off) incl += u;
    }
    if (lane == 63) swt[w] = incl;
    __syncthreads();
    int waveoff = 0;
    for (int k = 0; k < w; ++k) waveoff += swt[k];
    int run = waveoff + incl - c;   // exclusive prefix within bucket
    ptr[t] = run;
    if (rowLo + t < totalRows) rowptr[rowLo + t] = bb + run;
    __syncthreads();
    for (int i = t; i < bsz; i += 256) {
        int2 e = bcv[bb + i];
        int lrow = ((unsigned)e.x) >> 24;
        int pos = atomicAdd(&ptr[lrow], 1);
        edg[bb + pos] = make_int2(e.x & 0x00FFFFFF, e.y);
    }
}

// ---------------- GEMM: Y(MxC) = A(MxC) @ B(CxC), multi-job ----------------
// BM=64 tile: sA 16KB + sB 32KB = 48KB LDS -> 3 blocks/CU (12 waves) vs the
// 128-tile's 2 blocks. B stays in LDS (R10 showed direct-global B exposes
// L2 latency per MFMA and regresses). Each of 4 waves owns one 16-row strip.

__device__ __forceinline__ int lds_idx(int r, int koff) {
    return (r << 7) + ((((koff >> 3) ^ (r & 15))) << 3);
}

__device__ __forceinline__ void gemm_core64(const unsigned short* sA, const unsigned short* sB,
                                            unsigned short* __restrict__ Y, int M, int row0, int t) {
    const int wave = t >> 6;
    const int lane = t & 63;
    const int quad = lane >> 4;
    const int l16  = lane & 15;

    floatx4 acc[8];
#pragma unroll
    for (int j = 0; j < 8; ++j) acc[j] = (floatx4){0.f, 0.f, 0.f, 0.f};

    const int arow = wave * 16 + l16;
#pragma unroll
    for (int kk = 0; kk < 4; ++kk) {
        int ko = kk * 32 + quad * 8;
        short8 a = *(const short8*)(&sA[lds_idx(arow, ko)]);
#pragma unroll
        for (int j = 0; j < 8; ++j) {
            short8 b = *(const short8*)(&sB[lds_idx(j * 16 + l16, ko)]);
            acc[j] = __builtin_amdgcn_mfma_f32_16x16x32_bf16(a, b, acc[j], 0, 0, 0);
        }
    }

    int rg0 = row0 + wave * 16 + quad * 4;
#pragma unroll
    for (int reg = 0; reg < 4; ++reg) {
        int rg = rg0 + reg;
        if (rg >= M) continue;
        unsigned short* yr = Y + (size_t)rg * CH;
#pragma unroll
        for (int j = 0; j < 8; ++j)
            yr[j * 16 + l16] = f2bf(acc[j][reg]);
    }
}

struct GJobs {
    const void* A[6];
    const unsigned short* Bt[6];
    unsigned short* Y[6];
    int M[6];
    int bstart[7];   // bstart[njobs] = total blocks
    int njobs;
};

__global__ __launch_bounds__(256) void k_gemm_multi(GJobs g) {
    __shared__ __align__(16) unsigned short sA[64 * 128];
    __shared__ __align__(16) unsigned short sB[128 * 128];
    const int t = threadIdx.x;
    int b = blockIdx.x;
    int j = 0;
    while (j + 1 < g.njobs && b >= g.bstart[j + 1]) ++j;
    const unsigned short* A = (const unsigned short*)g.A[j];
    const unsigned short* Bt = g.Bt[j];
    unsigned short* Y = g.Y[j];
    int M = g.M[j];
    const int row0 = (b - g.bstart[j]) * 64;

#pragma unroll
    for (int it = 0; it < 8; ++it) {            // sB: 128 rows
        int chunk = it * 256 + t;
        int r = chunk >> 4;
        int cidx = chunk & 15;
        int coff = cidx << 3;
        int sidx = (r << 7) + (((cidx ^ (r & 15))) << 3);
        *(float4*)(&sB[sidx]) = *(const float4*)(Bt + (r << 7) + coff);
    }
#pragma unroll
    for (int it = 0; it < 4; ++it) {            // sA: 64 rows
        int chunk = it * 256 + t;
        int r = chunk >> 4;
        int cidx = chunk & 15;
        int coff = cidx << 3;
        int sidx = (r << 7) + (((cidx ^ (r & 15))) << 3);
        int gr = row0 + r;
        float4 av = make_float4(0.f, 0.f, 0.f, 0.f);
        if (gr < M) av = *(const float4*)(A + (size_t)gr * CH + coff);
        *(float4*)(&sA[sidx]) = av;
    }
    __syncthreads();
    gemm_core64(sA, sB, Y, M, row0, t);
}

// A in f32 (layer-1 inputs); converts to bf16 during staging
__global__ __launch_bounds__(256) void k_gemm_multi_f32(GJobs g) {
    __shared__ __align__(16) unsigned short sA[64 * 128];
    __shared__ __align__(16) unsigned short sB[128 * 128];
    const int t = threadIdx.x;
    int b = blockIdx.x;
    int j = 0;
    while (j + 1 < g.njobs && b >= g.bstart[j + 1]) ++j;
    const float* A = (const float*)g.A[j];
    const unsigned short* Bt = g.Bt[j];
    unsigned short* Y = g.Y[j];
    int M = g.M[j];
    const int row0 = (b - g.bstart[j]) * 64;

#pragma unroll
    for (int it = 0; it < 8; ++it) {            // sB: 128 rows
        int chunk = it * 256 + t;
        int r = chunk >> 4;
        int cidx = chunk & 15;
        int coff = cidx << 3;
        int sidx = (r << 7) + (((cidx ^ (r & 15))) << 3);
        *(float4*)(&sB[sidx]) = *(const float4*)(Bt + (r << 7) + coff);
    }
#pragma unroll
    for (int it = 0; it < 4; ++it) {            // sA: 64 rows, f32 -> bf16
        int chunk = it * 256 + t;
        int r = chunk >> 4;
        int cidx = chunk & 15;
        int coff = cidx << 3;
        int sidx = (r << 7) + (((cidx ^ (r & 15))) << 3);
        int gr = row0 + r;
        unsigned short us[8];
        if (gr < M) {
            const float* ar = A + (size_t)gr * CH + coff;
            float4 f0 = *(const float4*)ar;
            float4 f1 = *(const float4*)(ar + 4);
            us[0] = f2bf(f0.x); us[1] = f2bf(f0.y); us[2] = f2bf(f0.z); us[3] = f2bf(f0.w);
            us[4] = f2bf(f1.x); us[5] = f2bf(f1.y); us[6] = f2bf(f1.z); us[7] = f2bf(f1.w);
        } else {
            for (int k = 0; k < 8; ++k) us[k] = 0;
        }
        *(float4*)(&sA[sidx]) = *(const float4*)us;
    }
    __syncthreads();
    gemm_core64(sA, sB, Y, M, row0, t);
}

// ---------------- fused gather + sigmoid (unified edge list) --------------
// one wave per unified row (~12 edges, one contiguous range, one y arena).
// 8-wide double-buffered pipeline: batch k+1's 8 gathers are issued before
// batch k's FMAs, so 8-16 loads are in flight per wave.

__device__ __forceinline__ void g_load(const int2* __restrict__ eg, int j, int n,
                                       const unsigned short* __restrict__ y, int coff,
                                       int2* e, unsigned int* u) {
#pragma unroll
    for (int k = 0; k < 8; ++k) {
        if (k < n) {
            e[k] = eg[j + k];
            u[k] = *(const unsigned int*)(y + (((size_t)(unsigned)e[k].x) << 7) + coff);
        }
    }
}

__device__ __forceinline__ void g_acc(const int2* e, const unsigned int* u, int n,
                                      float& a0, float& a1) {
#pragma unroll
    for (int k = 0; k < 8; ++k) {
        if (k < n) {
            float v = __int_as_float(e[k].y);
            a0 += v * __int_as_float(u[k] << 16);
            a1 += v * __int_as_float(u[k] & 0xffff0000u);
        }
    }
}

__global__ __launch_bounds__(256) void k_gather(
    const int* __restrict__ rp, const unsigned short* __restrict__ y,
    const int2* __restrict__ eArena,
    unsigned short* __restrict__ xout, int M)
{
    int wrow = blockIdx.x * 4 + (threadIdx.x >> 6);
    if (wrow >= M) return;
    wrow = __builtin_amdgcn_readfirstlane(wrow);
    int lane = threadIdx.x & 63;
    int coff = lane * 2;
    float a0 = 0.f, a1 = 0.f;

    int jb = __builtin_amdgcn_readfirstlane(rp[wrow]);
    int je = __builtin_amdgcn_readfirstlane(rp[wrow + 1]);
    int j = jb;
    int2 ea[8]; unsigned int ua[8];
    int2 eb[8]; unsigned int ub[8];
    int n0 = je - j; if (n0 > 8) n0 = 8;
    if (n0 > 0) g_load(eArena, j, n0, y, coff, ea, ua);
    j += n0;
    while (j < je) {
        int n1 = je - j; if (n1 > 8) n1 = 8;
        g_load(eArena, j, n1, y, coff, eb, ub);
        j += n1;
        g_acc(ea, ua, n0, a0, a1);
#pragma unroll
        for (int k = 0; k < 8; ++k) {
            if (k < n1) { ea[k] = eb[k]; ua[k] = ub[k]; }
        }
        n0 = n1;
    }
    if (n0 > 0) g_acc(ea, ua, n0, a0, a1);

    float s0 = 1.0f / (1.0f + __expf(-a0));
    float s1 = 1.0f / (1.0f + __expf(-a1));
    ushort2 o;
    o.x = f2bf(s0);
    o.y = f2bf(s1);
    *(ushort2*)(xout + (size_t)wrow * CH + coff) = o;
}

// ---------------- output head ----------------

__global__ __launch_bounds__(128) void k_out(const unsigned short* __restrict__ x0,
                                             const float* __restrict__ Wout,
                                             const float* __restrict__ bout,
                                             float* __restrict__ out, int M) {
    __shared__ float sl[8][16];
    int rlocal = threadIdx.x >> 4;
    int o = threadIdx.x & 15;
    int rowi = blockIdx.x * 8 + rlocal;
    float acc = 0.f;
    if (rowi < M && o < 10) {
        const unsigned short* xr = x0 + (size_t)rowi * CH;
        for (int k = 0; k < CH; ++k)
            acc += bf2f(xr[k]) * Wout[k * 10 + o];
        acc += bout[o];
    }
    sl[rlocal][o] = acc;
    __syncthreads();
    if (rowi < M && o < 10) {
        float mx = -1e30f;
        for (int j = 0; j < 10; ++j) mx = fmaxf(mx, sl[rlocal][j]);
        float s = 0.f;
        for (int j = 0; j < 10; ++j) s += __expf(sl[rlocal][j] - mx);
        out[rowi * 10 + o] = __expf(sl[rlocal][o] - mx) / s;
    }
}

// ---------------- launch ----------------

extern "C" void kernel_launch(void* const* d_in, const int* in_sizes, int n_in,
                              void* d_out, int out_size, void* d_ws, size_t ws_size,
                              hipStream_t stream) {
    const float* xin[4];
    for (int r = 0; r < 4; ++r) xin[r] = (const float*)d_in[r];
    const int* arow[4]; const int* acol[4]; const float* aval[4];
    for (int r = 0; r < 4; ++r) {
        arow[r] = (const int*)d_in[4 + 3 * r];
        acol[r] = (const int*)d_in[5 + 3 * r];
        aval[r] = (const float*)d_in[6 + 3 * r];
    }
    const int* irow[3]; const int* icol[3]; const float* ival[3];
    for (int r = 0; r < 3; ++r) {
        irow[r] = (const int*)d_in[16 + 3 * r];
        icol[r] = (const int*)d_in[17 + 3 * r];
        ival[r] = (const float*)d_in[18 + 3 * r];
    }
    const float* W_same = (const float*)d_in[25];
    const float* W_h2l  = (const float*)d_in[26];
    const float* W_l2h  = (const float*)d_in[27];
    const float* W_out  = (const float*)d_in[28];
    const float* b_out  = (const float*)d_in[29];

    int Nr[4], adjnnz[4], incnnz[3];
    for (int r = 0; r < 4; ++r) { Nr[r] = in_sizes[r] / CH; adjnnz[r] = in_sizes[4 + 3 * r]; }
    for (int r = 0; r < 3; ++r) incnnz[r] = in_sizes[16 + 3 * r];
    size_t totalN = (size_t)Nr[0] + Nr[1] + Nr[2] + Nr[3];
    size_t totAdj = 0; for (int r = 0; r < 4; ++r) totAdj += adjnnz[r];
    size_t totInc = 0; for (int r = 0; r < 3; ++r) totInc += incnnz[r];
    size_t totEdges = totAdj + 2 * totInc;

    // unified row space: one row per (rank, simplex)
    int baseRank[4];
    int acc_rows = 0;
    for (int r = 0; r < 4; ++r) { baseRank[r] = acc_rows; acc_rows += Nr[r]; }
    int totalRowsU = acc_rows;               // == totalN
    int nbuk = (totalRowsU + RPB - 1) >> 8;

    // ---- y arena: 6 exact-size slots (S/H/L x even/odd target parity) ----
    auto imax = [](int a, int b) { return a > b ? a : b; };
    int szSe = imax(Nr[0], Nr[2]), szSo = imax(Nr[1], Nr[3]);
    int szHe = imax(Nr[1], Nr[3]), szHo = Nr[2];
    int szLe = Nr[1],              szLo = imax(Nr[0], Nr[2]);
    int bSe = 0;
    int bSo = bSe + szSe;
    int bHe = bSo + szSo;
    int bHo = bHe + szHe;
    int bLe = bHo + szHo;
    int bLo = bLe + szLe;
    int yRows = bLo + szLo;      // ~600K rows < 2^24

    // ---- workspace ----
    char* ws = (char*)d_ws;
    size_t off = 0;
    auto take = [&](size_t bytes) { char* p = ws + off; off += (bytes + 255) & ~(size_t)255; return p; };
    unsigned short* xbuf   = (unsigned short*)take(totalN * CH * 2);
    unsigned short* yArena = (unsigned short*)take((size_t)yRows * CH * 2);
    unsigned short* WT     = (unsigned short*)take((size_t)20 * 16384 * 2);
    int*  rowptrG = (int*)take(((size_t)totalRowsU + 1) * 4);
    int2* eArena  = (int2*)take(totEdges * 8);
    (void)ws_size;

    unsigned short* WsT = WT;                       // mats 0..7
    unsigned short* WhT = WT + ((size_t)8 << 14);   // mats 8..13
    unsigned short* WlT = WT + ((size_t)14 << 14);  // mats 14..19

    unsigned short* x[4];
    {
        size_t o = 0;
        for (int r = 0; r < 4; ++r) { x[r] = xbuf + o; o += (size_t)Nr[r] * CH; }
    }

    // ---- CSR build ----
    Segs sg;
    int nblk = 0;
    {
        for (int r = 0; r < 4; ++r) {  // adj: rows of rank r, reads S_r slot
            sg.row[r] = arow[r]; sg.col[r] = acol[r]; sg.val[r] = aval[r];
            sg.base[r] = baseRank[r];
            sg.coff[r] = (r & 1) ? bSo : bSe;
            sg.nnz[r] = adjnnz[r]; sg.start[r] = nblk;
            nblk += (adjnnz[r] + EPB - 1) / EPB;
        }
        for (int s = 0; s < 3; ++s) {  // h2l: rows of rank s, cols -> H_s slot
            sg.row[4 + s] = irow[s]; sg.col[4 + s] = icol[s]; sg.val[4 + s] = ival[s];
            sg.base[4 + s] = baseRank[s];
            sg.coff[4 + s] = (s & 1) ? bHo : bHe;
            sg.nnz[4 + s] = incnnz[s]; sg.start[4 + s] = nblk;
            nblk += (incnnz[s] + EPB - 1) / EPB;
        }
        for (int s = 0; s < 3; ++s) {  // l2h: rows of rank s+1, cols -> L_{s+1} slot
            sg.row[7 + s] = icol[s]; sg.col[7 + s] = irow[s]; sg.val[7 + s] = ival[s];
            sg.base[7 + s] = baseRank[s + 1];
            sg.coff[7 + s] = ((s + 1) & 1) ? bLo : bLe;
            sg.nnz[7 + s] = incnnz[s]; sg.start[7 + s] = nblk;
            nblk += (incnnz[s] + EPB - 1) / EPB;
        }

        // CSR-build scratch aliases buffers dead until the layer phase:
        //   bcv  (totEdges*8 = 25.6 MB) <- yArena
        //   M (nblk*nbuk*4 ~ 7 MB) + colsum + bucketBase <- xbuf
        int2* bcv = (int2*)yArena;
        int*  M   = (int*)xbuf;
        int*  colsum     = M + (size_t)nblk * nbuk;
        int*  bucketBase = colsum + nbuk;

        k_bkt_count  <<<nblk, 256, 0, stream>>>(sg, nbuk, M);
        k_colscan    <<<nbuk, 256, 0, stream>>>(M, nblk, nbuk, colsum);
        k_bkt_scan   <<<1,    256, 0, stream>>>(colsum, nbuk, bucketBase, rowptrG + totalRowsU);
        k_bkt_scatter<<<nblk, 256, 0, stream>>>(sg, nbuk, M, bucketBase, bcv);
        k_bkt_csr    <<<nbuk, 256, 0, stream>>>(bcv, bucketBase, rowptrG, totalRowsU, eArena);
    }

    // ---- weights ----
    k_wt_all<<<(20 * 16384 + 255) / 256, 256, 0, stream>>>(W_same, W_h2l, W_l2h, WT);

    // ---- layers: per layer only 4 dispatches ----
    // G01 = {S0,H0,L1, S1,H1,L2} -> g01 (ranks 0,1) -> G23 = {S2,H2,L3, S3} -> g23.
    // Even-parity slots written by G23 (S2,H2) reuse S0/H0's slots, consumed-
    // before-overwrite since g01 precedes G23; L slots: L1->Lo, L2->Le, L3->Lo.
    unsigned short* ySlotS[2] = { yArena + (size_t)bSe * CH, yArena + (size_t)bSo * CH };
    unsigned short* ySlotH[2] = { yArena + (size_t)bHe * CH, yArena + (size_t)bHo * CH };
    unsigned short* ySlotL[2] = { yArena + (size_t)bLe * CH, yArena + (size_t)bLo * CH };

    for (int l = 0; l < 2; ++l) {
        auto Ain = [&](int r) -> const void* {
            return (l == 0) ? (const void*)xin[r] : (const void*)x[r];
        };
        // ---- G01 ----
        {
            GJobs g; int nj = 0;
            auto add = [&](const void* A, const unsigned short* Bt, unsigned short* Y, int M) {
                g.A[nj] = A; g.Bt[nj] = Bt; g.Y[nj] = Y; g.M[nj] = M; ++nj;
            };
            add(Ain(0), WsT + (((size_t)(l * 4 + 0)) << 14), ySlotS[0], Nr[0]);  // S0
            add(Ain(1), WhT + (((size_t)(l * 3 + 0)) << 14), ySlotH[0], Nr[1]);  // H0
            add(Ain(0), WlT + (((size_t)(l * 3 + 0)) << 14), ySlotL[1], Nr[0]);  // L1
            add(Ain(1), WsT + (((size_t)(l * 4 + 1)) << 14), ySlotS[1], Nr[1]);  // S1
            add(Ain(2), WhT + (((size_t)(l * 3 + 1)) << 14), ySlotH[1], Nr[2]);  // H1
            add(Ain(1), WlT + (((size_t)(l * 3 + 1)) << 14), ySlotL[0], Nr[1]);  // L2
            g.njobs = nj;
            int bacc = 0;
            for (int k = 0; k < nj; ++k) { g.bstart[k] = bacc; bacc += (g.M[k] + 63) / 64; }
            g.bstart[nj] = bacc;
            if (l == 0) k_gemm_multi_f32<<<bacc, 256, 0, stream>>>(g);
            else        k_gemm_multi    <<<bacc, 256, 0, stream>>>(g);
        }
        {   // g01: ranks 0,1 -> x0|x1 (contiguous in xbuf)
            int Mg = Nr[0] + Nr[1];
            k_gather<<<(Mg + 3) / 4, 256, 0, stream>>>(rowptrG, yArena, eArena, xbuf, Mg);
        }
        // ---- G23 ----
        {
            GJobs g; int nj = 0;
            auto add = [&](const void* A, const unsigned short* Bt, unsigned short* Y, int M) {
                g.A[nj] = A; g.Bt[nj] = Bt; g.Y[nj] = Y; g.M[nj] = M; ++nj;
            };
            add(Ain(2), WsT + (((size_t)(l * 4 + 2)) << 14), ySlotS[0], Nr[2]);  // S2
            add(Ain(3), WhT + (((size_t)(l * 3 + 2)) << 14), ySlotH[0], Nr[3]);  // H2
            add(Ain(2), WlT + (((size_t)(l * 3 + 2)) << 14), ySlotL[1], Nr[2]);  // L3
            add(Ain(3), WsT + (((size_t)(l * 4 + 3)) << 14), ySlotS[1], Nr[3]);  // S3
            g.njobs = nj;
            int bacc = 0;
            for (int k = 0; k < nj; ++k) { g.bstart[k] = bacc; bacc += (g.M[k] + 63) / 64; }
            g.bstart[nj] = bacc;
            if (l == 0) k_gemm_multi_f32<<<bacc, 256, 0, stream>>>(g);
            else        k_gemm_multi    <<<bacc, 256, 0, stream>>>(g);
        }
        {   // g23: ranks 2,3 -> x2|x3 (contiguous in xbuf)
            int Mg = Nr[2] + Nr[3];
            k_gather<<<(Mg + 3) / 4, 256, 0, stream>>>(rowptrG + baseRank[2], yArena, eArena, x[2], Mg);
        }
    }

    k_out<<<(Nr[0] + 7) / 8, 128, 0, stream>>>(x[0], W_out, b_out, (float*)d_out, Nr[0]);
}